// Round 9
// baseline (46.891 us; speedup 1.0000x reference)
//
#include <hip/hip_runtime.h>

typedef __attribute__((ext_vector_type(8))) short bf16x8_t;   // 8 bf16 (4 VGPRs)
typedef __attribute__((ext_vector_type(4))) float f32x4_t;    // MFMA accumulator

__device__ __forceinline__ unsigned short f2bf(float f) {
    union { float f; unsigned int i; } v; v.f = f;
    unsigned int u = v.i;
    return (unsigned short)((u + 0x7FFFu + ((u >> 16) & 1u)) >> 16);   // RNE
}

__device__ __forceinline__ unsigned int cvt_pk_bf16(float lo, float hi) {
    unsigned int r;
    asm("v_cvt_pk_bf16_f32 %0, %1, %2" : "=v"(r) : "v"(lo), "v"(hi));
    return r;
}

#define LD4(p) (*reinterpret_cast<const float4*>(p))

// d_ws layout (u16): [0..1024) W1p h-MFMA A-frags; [1024..9728) W2p B-frags.
// tab total: 19 fragment-sets x 64 lanes x 8 u16 = 19456 B.

// ============ kernel 1: fused {root-init | fragment-table prep} ============
__global__ __launch_bounds__(256) void prep_kernel(
    const float* __restrict__ x,
    const float* __restrict__ W1,      // [8,32]
    const float* __restrict__ b1,      // [32]
    const float* __restrict__ W2,      // [32,256]
    const float* __restrict__ b2,      // [256]
    const float* __restrict__ rootk,   // [16,16]
    const float* __restrict__ bias,    // [16]
    float* __restrict__ out,           // [N,16]
    unsigned short* __restrict__ tab,
    int n_nodes, int root_blocks)
{
    const int tid = threadIdx.x;
    const int bid = blockIdx.x;

    if (bid < root_blocks) {
        __shared__ float sR[256];
        __shared__ float sB[16];
        if (tid < 256) sR[tid] = rootk[tid];
        if (tid < 16)  sB[tid] = bias[tid];
        __syncthreads();

        int nid = bid * 256 + tid;
        if (nid >= n_nodes) return;

        const float* xp = x + (size_t)nid * 16;
        float xf[16];
#pragma unroll
        for (int f = 0; f < 16; f += 4) {
            float4 v = LD4(xp + f);
            xf[f] = v.x; xf[f + 1] = v.y; xf[f + 2] = v.z; xf[f + 3] = v.w;
        }
        float o[16];
#pragma unroll
        for (int cc = 0; cc < 16; ++cc) o[cc] = sB[cc];
#pragma unroll
        for (int f = 0; f < 16; ++f) {
            float p = xf[f];
#pragma unroll
            for (int cc = 0; cc < 16; ++cc)
                o[cc] = fmaf(p, sR[f * 16 + cc], o[cc]);
        }
        float* dst = out + (size_t)nid * 16;
#pragma unroll
        for (int cc = 0; cc < 16; cc += 4)
            *reinterpret_cast<float4*>(dst + cc) = make_float4(o[cc], o[cc+1], o[cc+2], o[cc+3]);
    } else {
        // ---- fragment tables: 19 groups of 64 lanes ----
        for (int it = tid; it < 64 * 19; it += 256) {
            int grp  = it >> 6;         // 0,1 -> W1p halves; 2..18 -> W2p steps
            int lane = it & 63;
            int q = lane >> 4, cc = lane & 15;
            union { unsigned short h[8]; uint4 u; } pk;
            if (grp < 2) {
                int hh = grp;
#pragma unroll
                for (int j = 0; j < 8; ++j) {
                    float v = 0.f;
                    if (q == 0)              v = W1[j * 32 + cc + 16 * hh];
                    else if (q == 1 && j==0) v = b1[cc + 16 * hh];
                    pk.h[j] = f2bf(v);
                }
                *reinterpret_cast<uint4*>(tab + ((size_t)hh * 64 + lane) * 8) = pk.u;
            } else {
                int s = grp - 2;        // K-step
#pragma unroll
                for (int j = 0; j < 8; ++j) {
                    float v;
                    if (s < 16) {
                        int hd = (j < 4) ? (4 * q + j) : (4 * q + 12 + j);  // perm
                        v = W2[hd * 256 + s * 16 + cc];
                    } else {
                        v = (q < 2) ? b2[(q * 8 + j) * 16 + cc] : 0.f;       // b2 fold
                    }
                    pk.h[j] = f2bf(v);
                }
                *reinterpret_cast<uint4*>(tab + 1024 + ((size_t)s * 64 + lane) * 8) = pk.u;
            }
        }
    }
}

// ============ kernel 2: MFMA edge kernel — B-frags in LDS, 4 groups/wave straight-line ============
template<int EXACT>
__global__ __launch_bounds__(256, 4) void edge_mfma_kernel(
    const float* __restrict__ x,       // [N,16]
    const float* __restrict__ efeat,   // [E,8]
    const int*   __restrict__ idx_i,
    const int*   __restrict__ idx_j,
    const unsigned short* __restrict__ tab,
    float* __restrict__ out,           // [N,16], pre-initialized with root term
    int n_edges, int n_groups)
{
    // ---- stage all fragment tables into LDS (19456 B, shared by 4 waves) ----
    __shared__ __align__(16) unsigned short sTab[19 * 64 * 8];
    {
        const uint4* gsrc = reinterpret_cast<const uint4*>(tab);
        uint4* gdst = reinterpret_cast<uint4*>(sTab);
        for (int i = threadIdx.x; i < 19 * 64; i += 256) gdst[i] = gsrc[i];
    }
    __syncthreads();

    const int lane = threadIdx.x & 63;
    const int q = lane >> 4;
    const int c = lane & 15;

    const bf16x8_t* sfr = reinterpret_cast<const bf16x8_t*>(sTab);
    // h-MFMA A-frags stay in registers (only 8 regs)
    const bf16x8_t aW1_0 = sfr[lane];
    const bf16x8_t aW1_1 = sfr[64 + lane];
    // W2 B-frags read from LDS per K-step:
    const bf16x8_t* bw = sfr + 128 + lane;

    const unsigned int c1 = (q == 1) ? 0x00003F80u : 0u;   // bf16(1.0) one-hot for b1 row
    const bool isq0 = (q == 0);
    const bool qodd = (q & 1);
    float* const outc = out + c;

    const int wid = blockIdx.x * 4 + (threadIdx.x >> 6);
    const int g0  = wid * 4;
    if (g0 >= n_groups) return;
    const int rem = n_groups - g0;   // >= 1

    auto ldj = [&](int gg) -> int {
        int eid = gg * 16 + c;
        if (!EXACT) { if (eid >= n_edges) eid = n_edges - 1; }
        return idx_j[eid];
    };
    auto eoff = [&](int gg) -> size_t {
        int eid = gg * 16 + c;
        if (!EXACT) { if (eid >= n_edges) eid = n_edges - 1; }
        return (size_t)eid * 8;
    };

    auto compute = [&](float4 X0, float4 X1, float4 X2, float4 X3,
                       float4 E0, float4 E1, int gg) {
        // idx_i: issued now, consumed only at the very end (self-hiding)
        int t0, t1, t2, t3;
        if (EXACT || (gg * 16 + 16 <= n_edges)) {
            int4 tv = *reinterpret_cast<const int4*>(idx_i + gg * 16 + q * 4);
            t0 = tv.x; t1 = tv.y; t2 = tv.z; t3 = tv.w;
        } else {
            const int eb = gg * 16 + q * 4;
            t0 = (eb + 0 < n_edges) ? idx_i[eb + 0] : 0;
            t1 = (eb + 1 < n_edges) ? idx_i[eb + 1] : 0;
            t2 = (eb + 2 < n_edges) ? idx_i[eb + 2] : 0;
            t3 = (eb + 3 < n_edges) ? idx_i[eb + 3] : 0;
        }

        // ---- h via MFMA: lane owns hd {4q..4q+3, 4q+16..4q+19} ----
        union { bf16x8_t bf; unsigned int u[4]; } bB;
        {
            unsigned int ef0 = cvt_pk_bf16(E0.x, E0.y);
            unsigned int ef1 = cvt_pk_bf16(E0.z, E0.w);
            unsigned int ef2 = cvt_pk_bf16(E1.x, E1.y);
            unsigned int ef3 = cvt_pk_bf16(E1.z, E1.w);
            bB.u[0] = isq0 ? ef0 : c1;
            bB.u[1] = isq0 ? ef1 : 0u;
            bB.u[2] = isq0 ? ef2 : 0u;
            bB.u[3] = isq0 ? ef3 : 0u;
        }
        f32x4_t z4 = {0.f, 0.f, 0.f, 0.f};
        f32x4_t h0 = __builtin_amdgcn_mfma_f32_16x16x32_bf16(aW1_0, bB.bf, z4, 0, 0, 0);
        f32x4_t h1 = __builtin_amdgcn_mfma_f32_16x16x32_bf16(aW1_1, bB.bf, z4, 0, 0, 0);

        float hown[8];
#pragma unroll
        for (int r = 0; r < 4; ++r) {
            hown[r]     = fmaxf(h0[r], 0.f);
            hown[4 + r] = fmaxf(h1[r], 0.f);
        }

        float xf[16];
        xf[0]=X0.x; xf[1]=X0.y; xf[2]=X0.z; xf[3]=X0.w;
        xf[4]=X1.x; xf[5]=X1.y; xf[6]=X1.z; xf[7]=X1.w;
        xf[8]=X2.x; xf[9]=X2.y; xf[10]=X2.z; xf[11]=X2.w;
        xf[12]=X3.x; xf[13]=X3.y; xf[14]=X3.z; xf[15]=X3.w;
        // (garbage rows for invalid edges are harmless: D rows are per-edge,
        //  and invalid rows' atomics are guarded below)

        // ---- b2-fold A fragment ----
        union { bf16x8_t bf; unsigned int u[4]; } xb;
        xb.u[0] = cvt_pk_bf16(qodd ? xf[8]  : xf[0], qodd ? xf[9]  : xf[1]);
        xb.u[1] = cvt_pk_bf16(qodd ? xf[10] : xf[2], qodd ? xf[11] : xf[3]);
        xb.u[2] = cvt_pk_bf16(qodd ? xf[12] : xf[4], qodd ? xf[13] : xf[5]);
        xb.u[3] = cvt_pk_bf16(qodd ? xf[14] : xf[6], qodd ? xf[15] : xf[7]);

        // ---- K loop: A[c][q*8+j] = bf16(hown[j] * x[f=s]); B frags from LDS ----
        f32x4_t acc0 = {0.f, 0.f, 0.f, 0.f};
        f32x4_t acc1 = {0.f, 0.f, 0.f, 0.f};
        union { bf16x8_t bf; unsigned int u[4]; } afr;
#pragma unroll 4
        for (int s = 0; s < 16; s += 2) {
            float xs = xf[s];
            afr.u[0] = cvt_pk_bf16(hown[0] * xs, hown[1] * xs);
            afr.u[1] = cvt_pk_bf16(hown[2] * xs, hown[3] * xs);
            afr.u[2] = cvt_pk_bf16(hown[4] * xs, hown[5] * xs);
            afr.u[3] = cvt_pk_bf16(hown[6] * xs, hown[7] * xs);
            acc0 = __builtin_amdgcn_mfma_f32_16x16x32_bf16(afr.bf, bw[s * 64], acc0, 0, 0, 0);
            xs = xf[s + 1];
            afr.u[0] = cvt_pk_bf16(hown[0] * xs, hown[1] * xs);
            afr.u[1] = cvt_pk_bf16(hown[2] * xs, hown[3] * xs);
            afr.u[2] = cvt_pk_bf16(hown[4] * xs, hown[5] * xs);
            afr.u[3] = cvt_pk_bf16(hown[6] * xs, hown[7] * xs);
            acc1 = __builtin_amdgcn_mfma_f32_16x16x32_bf16(afr.bf, bw[(s + 1) * 64], acc1, 0, 0, 0);
        }
        acc0 = __builtin_amdgcn_mfma_f32_16x16x32_bf16(xb.bf, bw[16 * 64], acc0, 0, 0, 0);

        const float rr0 = acc0[0] + acc1[0];
        const float rr1 = acc0[1] + acc1[1];
        const float rr2 = acc0[2] + acc1[2];
        const float rr3 = acc0[3] + acc1[3];
        if (EXACT) {
            atomicAdd(outc + (size_t)t0 * 16, rr0);
            atomicAdd(outc + (size_t)t1 * 16, rr1);
            atomicAdd(outc + (size_t)t2 * 16, rr2);
            atomicAdd(outc + (size_t)t3 * 16, rr3);
        } else {
            const int eb = gg * 16 + q * 4;
            if (eb + 0 < n_edges) atomicAdd(outc + (size_t)t0 * 16, rr0);
            if (eb + 1 < n_edges) atomicAdd(outc + (size_t)t1 * 16, rr1);
            if (eb + 2 < n_edges) atomicAdd(outc + (size_t)t2 * 16, rr2);
            if (eb + 3 < n_edges) atomicAdd(outc + (size_t)t3 * 16, rr3);
        }
    };

#define STAGE(B0,B1,B2,B3,BE0,BE1, jv, gg)                         \
    {                                                              \
        const float* xp = x + (size_t)(jv) * 16;                   \
        B0 = LD4(xp); B1 = LD4(xp + 4);                            \
        B2 = LD4(xp + 8); B3 = LD4(xp + 12);                       \
        const float* ep = efeat + eoff(gg);                        \
        BE0 = LD4(ep); BE1 = LD4(ep + 4);                          \
    }

    // ---- all 4 source indices in flight first ----
    const int jA = ldj(g0);
    const int jB = (rem > 1) ? ldj(g0 + 1) : 0;
    const int jC = (rem > 2) ? ldj(g0 + 2) : 0;
    const int jD = (rem > 3) ? ldj(g0 + 3) : 0;

    float4 a0, a1, a2, a3, ae0, ae1;
    float4 b0, b1, b2, b3, be0, be1;

    STAGE(a0,a1,a2,a3,ae0,ae1, jA, g0);
    if (rem > 1) STAGE(b0,b1,b2,b3,be0,be1, jB, g0 + 1);
    compute(a0,a1,a2,a3,ae0,ae1, g0);
    if (rem > 1) {
        if (rem > 2) STAGE(a0,a1,a2,a3,ae0,ae1, jC, g0 + 2);
        compute(b0,b1,b2,b3,be0,be1, g0 + 1);
        if (rem > 2) {
            if (rem > 3) STAGE(b0,b1,b2,b3,be0,be1, jD, g0 + 3);
            compute(a0,a1,a2,a3,ae0,ae1, g0 + 2);
            if (rem > 3) compute(b0,b1,b2,b3,be0,be1, g0 + 3);
        }
    }
#undef STAGE
}

extern "C" void kernel_launch(void* const* d_in, const int* in_sizes, int n_in,
                              void* d_out, int out_size, void* d_ws, size_t ws_size,
                              hipStream_t stream) {
    const float* x     = (const float*)d_in[0];
    const float* e     = (const float*)d_in[1];
    const int*   idx_i = (const int*)d_in[2];
    const int*   idx_j = (const int*)d_in[3];
    const float* W1    = (const float*)d_in[4];
    const float* b1    = (const float*)d_in[5];
    const float* W2    = (const float*)d_in[6];
    const float* b2    = (const float*)d_in[7];
    const float* rootk = (const float*)d_in[8];
    const float* bias  = (const float*)d_in[9];

    int n_nodes  = in_sizes[0] / 16;
    int n_edges  = in_sizes[2];
    int n_groups = (n_edges + 15) / 16;

    float* out = (float*)d_out;
    unsigned short* tab = (unsigned short*)d_ws;   // 19.5 KB used

    int root_blocks = (n_nodes + 255) / 256;
    prep_kernel<<<root_blocks + 1, 256, 0, stream>>>(x, W1, b1, W2, b2, rootk, bias,
                                                     out, tab, n_nodes, root_blocks);

    // 4 waves/block, 4 contiguous groups per wave
    int blocks = (n_groups + 15) / 16;
    if ((n_edges & 15) == 0)
        edge_mfma_kernel<1><<<blocks, 256, 0, stream>>>(x, e, idx_i, idx_j, tab, out,
                                                        n_edges, n_groups);
    else
        edge_mfma_kernel<0><<<blocks, 256, 0, stream>>>(x, e, idx_i, idx_j, tab, out,
                                                        n_edges, n_groups);
}